// Round 10
// baseline (1344.319 us; speedup 1.0000x reference)
//
#include <hip/hip_runtime.h>
#include <hip/hip_fp16.h>

#define T_STEPS 512
#define BATCH   64
#define HID     512

// ---- scan11 geometry: grid=4 blocks x 16 batches, 8 waves x 64 rows ----
// R9 post-mortem: scan10's acc-major chains read bfr 63x/wave/step ->
// LDS pipe 504 KB/step/CU (~4000 clk) was the binding resource.
// scan11: per-ki grouping -> bfr read ONCE per ki, feeds all 4 accs:
//   31 ds_read_b128/wave/step (16 bfr + 15 a3) = 248 KB/step/CU.
// W split: tau0+tau1 (32 sets) AGPR-pinned (128 AGPR; feasible: arch ~90)
//          tau2 ki0..14 (15 sets) in LDS (120 KB)
//          tau3 ki0..15 + tau2 ki15 (17 sets) streamed, rolling 4-deep
//          window (16 VGPR staging instead of scan10's 100).
// h double-buffered (2 x 16 KB) -> ONE barrier/step.
#define NB      16
#define ALD     15

// ---- scan4 (fallback) W-row split ----
#define SCH_REG  40
#define SCH_LDS  10
#define SCH_SA   7
#define SCH_SB   7

// Workspace layout (unchanged, ~34.6 MB):
#define XP16_OFF  0u
#define XP16_BYTES (16777216u * 2u)         // 32 MB f16 xp (chunk layout)
#define WIH_OFF   (XP16_OFF + XP16_BYTES)
#define WIH_BYTES (262144u * 2u)
#define WHH_OFF   (WIH_OFF + WIH_BYTES)
#define WHH_BYTES (262144u * 2u)
#define WS_FULL   (WHH_OFF + WHH_BYTES)

typedef _Float16 half2v  __attribute__((ext_vector_type(2)));
typedef _Float16 half4v  __attribute__((ext_vector_type(4)));
typedef _Float16 half8   __attribute__((ext_vector_type(8)));
typedef short    short8  __attribute__((ext_vector_type(8)));
typedef float    f32x4   __attribute__((ext_vector_type(4)));
union F4H  { float4 f; half2v h[4]; };

__device__ inline float dot2f(half2v a, half2v b, float c) {
    return __builtin_amdgcn_fdot2(a, b, c, false);
}
__device__ inline unsigned short f2bf(float f) {
    unsigned u = __builtin_bit_cast(unsigned, f);
    return (unsigned short)((u + 0x7FFFu + ((u >> 16) & 1u)) >> 16);
}

// ---------------------------------------------------------------------------
// Conversions (re-run every call; ws is re-poisoned by the harness).
// ---------------------------------------------------------------------------
__global__ __launch_bounds__(256) void cvt_f16(const float* __restrict__ w,
                                               __half* __restrict__ o) {
    const int i = (blockIdx.x * 256 + threadIdx.x) * 4;
    float4 v = *(const float4*)(w + i);
    __half2 p0; p0.x = __float2half(v.x); p0.y = __float2half(v.y);
    __half2 p1; p1.x = __float2half(v.z); p1.y = __float2half(v.w);
    *(__half2*)(o + i)     = p0;
    *(__half2*)(o + i + 2) = p1;
}

__global__ __launch_bounds__(256) void cvt_bf16(const float* __restrict__ s,
                                                unsigned short* __restrict__ o) {
    const int i = (blockIdx.x * 256 + threadIdx.x) * 4;
    float4 v = *(const float4*)(s + i);
    ushort4 r = {f2bf(v.x), f2bf(v.y), f2bf(v.z), f2bf(v.w)};
    *(ushort4*)(o + i) = r;
}

// ---------------------------------------------------------------------------
// xproj via bf16 MFMA. Reads x f32 (converts in staging), writes f16 xp16
// in the scan's chunk layout:
//   half-index(t,b,o) = t*32768 + (b>>4)*8192 + (o>>3)*128 + (b&15)*8 + (o&7)
// ---------------------------------------------------------------------------
__global__ __launch_bounds__(256) void xproj_mfma(
    const float* __restrict__ x,
    const unsigned short* __restrict__ w16,
    const float* __restrict__ b_ih, const float* __restrict__ b_hh,
    __half* __restrict__ xp16)
{
    __shared__ __align__(16) unsigned short As[128][40];
    __shared__ __align__(16) unsigned short Bs[128][40];

    const int tid   = threadIdx.x;
    const int mBase = blockIdx.y * 128;
    const int nBase = blockIdx.x * 128;
    const int wave  = tid >> 6, lane = tid & 63;
    const int wy    = wave >> 1, wx = wave & 1;
    const int quad  = lane >> 4, l15 = lane & 15;
    const int lr    = tid >> 2;
    const int lk    = (tid & 3) * 8;

    f32x4 acc[4][4] = {};

    const size_t arow0 = (size_t)(mBase + lr) * 512 + lk;
    const size_t brow0 = (size_t)(nBase + lr) * 512 + lk;

    for (int k0 = 0; k0 < 512; k0 += 32) {
        float4 a0l = *(const float4*)(x + arow0 + k0);
        float4 a0h = *(const float4*)(x + arow0 + k0 + 4);
        float4 a1l = *(const float4*)(x + arow0 + (size_t)64 * 512 + k0);
        float4 a1h = *(const float4*)(x + arow0 + (size_t)64 * 512 + k0 + 4);
        int4 b0 = *(const int4*)(w16 + brow0 + k0);
        int4 b1 = *(const int4*)(w16 + brow0 + (size_t)64 * 512 + k0);
        int4 A0, A1;
        A0.x = f2bf(a0l.x) | ((unsigned)f2bf(a0l.y) << 16);
        A0.y = f2bf(a0l.z) | ((unsigned)f2bf(a0l.w) << 16);
        A0.z = f2bf(a0h.x) | ((unsigned)f2bf(a0h.y) << 16);
        A0.w = f2bf(a0h.z) | ((unsigned)f2bf(a0h.w) << 16);
        A1.x = f2bf(a1l.x) | ((unsigned)f2bf(a1l.y) << 16);
        A1.y = f2bf(a1l.z) | ((unsigned)f2bf(a1l.w) << 16);
        A1.z = f2bf(a1h.x) | ((unsigned)f2bf(a1h.y) << 16);
        A1.w = f2bf(a1h.z) | ((unsigned)f2bf(a1h.w) << 16);
        __syncthreads();
        *(int4*)&As[lr][lk]      = A0;
        *(int4*)&As[lr + 64][lk] = A1;
        *(int4*)&Bs[lr][lk]      = b0;
        *(int4*)&Bs[lr + 64][lk] = b1;
        __syncthreads();

        short8 af[4], bf[4];
#pragma unroll
        for (int mt = 0; mt < 4; ++mt)
            af[mt] = *(const short8*)&As[wy * 64 + mt * 16 + l15][quad * 8];
#pragma unroll
        for (int nt = 0; nt < 4; ++nt)
            bf[nt] = *(const short8*)&Bs[wx * 64 + nt * 16 + l15][quad * 8];
#pragma unroll
        for (int mt = 0; mt < 4; ++mt)
#pragma unroll
            for (int nt = 0; nt < 4; ++nt)
                acc[mt][nt] = __builtin_amdgcn_mfma_f32_16x16x32_bf16(
                    af[mt], bf[nt], acc[mt][nt], 0, 0, 0);
    }

    float bias[4]; int coln[4];
#pragma unroll
    for (int nt = 0; nt < 4; ++nt) {
        coln[nt] = nBase + wx * 64 + nt * 16 + l15;
        bias[nt] = b_ih[coln[nt]] + b_hh[coln[nt]];
    }
#pragma unroll
    for (int mt = 0; mt < 4; ++mt)
#pragma unroll
        for (int r = 0; r < 4; ++r) {
            const int m = mBase + wy * 64 + mt * 16 + quad * 4 + r;
            const int tt = m >> 6, b = m & 63;
#pragma unroll
            for (int nt = 0; nt < 4; ++nt) {
                const int o = coln[nt];
                const size_t idx = (size_t)tt * 32768 + (size_t)(b >> 4) * 8192
                                 + (o >> 3) * 128 + (b & 15) * 8 + (o & 7);
                xp16[idx] = __float2half(acc[mt][nt][r] + bias[nt]);
            }
        }
}

// ---------------------------------------------------------------------------
// Fallback fp32 xproj (writes f32 xproj into out, scan4-compatible).
// ---------------------------------------------------------------------------
__global__ __launch_bounds__(256) void xproj_gemm(
    const float* __restrict__ x, const float* __restrict__ w_ih,
    const float* __restrict__ b_ih, const float* __restrict__ b_hh,
    float* __restrict__ out)
{
    __shared__ __align__(16) float As[16][68];
    __shared__ __align__(16) float Bs[16][68];

    const int tid   = threadIdx.x;
    const int tx    = tid & 15;
    const int ty    = tid >> 4;
    const int mBase = blockIdx.y * 64;
    const int nBase = blockIdx.x * 64;
    const int ldr   = tid >> 2;
    const int ldk   = (tid & 3) * 4;

    float acc[4][4] = {};
    const float* aptr = x    + (size_t)(mBase + ldr) * 512 + ldk;
    const float* bptr = w_ih + (size_t)(nBase + ldr) * 512 + ldk;

    for (int k0 = 0; k0 < 512; k0 += 16) {
        float4 av = *(const float4*)(aptr + k0);
        float4 bv = *(const float4*)(bptr + k0);
        __syncthreads();
        As[ldk + 0][ldr] = av.x; As[ldk + 1][ldr] = av.y;
        As[ldk + 2][ldr] = av.z; As[ldk + 3][ldr] = av.w;
        Bs[ldk + 0][ldr] = bv.x; Bs[ldk + 1][ldr] = bv.y;
        Bs[ldk + 2][ldr] = bv.z; Bs[ldk + 3][ldr] = bv.w;
        __syncthreads();
#pragma unroll
        for (int kk = 0; kk < 16; ++kk) {
            float4 a = *(const float4*)&As[kk][ty * 4];
            float4 b = *(const float4*)&Bs[kk][tx * 4];
            float ar[4] = {a.x, a.y, a.z, a.w};
            float br[4] = {b.x, b.y, b.z, b.w};
#pragma unroll
            for (int i = 0; i < 4; ++i)
#pragma unroll
                for (int j = 0; j < 4; ++j)
                    acc[i][j] = fmaf(ar[i], br[j], acc[i][j]);
        }
    }
    const int n0 = nBase + tx * 4;
    float bias[4];
#pragma unroll
    for (int j = 0; j < 4; ++j) bias[j] = b_ih[n0 + j] + b_hh[n0 + j];
#pragma unroll
    for (int i = 0; i < 4; ++i) {
        const int m = mBase + ty * 4 + i;
        float4 v = {acc[i][0] + bias[0], acc[i][1] + bias[1],
                    acc[i][2] + bias[2], acc[i][3] + bias[3]};
        *(float4*)(out + (size_t)m * 512 + n0) = v;
    }
}

// ---------------------------------------------------------------------------
// Scan v11: per-ki-grouped MFMA (minimal LDS traffic) + rolling W stream.
// Per ki group: 1 bfr ds_read feeds all 4 accs; 1 a3 ds_read (tau2);
// tau3 from a rolling 4-deep streamed window (issued 3 groups ahead).
// ---------------------------------------------------------------------------
__global__
__attribute__((amdgpu_flat_work_group_size(512, 512)))
__attribute__((amdgpu_waves_per_eu(1, 2)))
void rnn_scan11(const __half* __restrict__ whh16,
                const __half* __restrict__ xp16,
                float* __restrict__ out)
{
    __shared__ __align__(16) _Float16 hlds[2][64 * NB * 8];       // 32 KB
    __shared__ __align__(16) _Float16 alds[8 * ALD * 512];        // 120 KB

    const int bg   = blockIdx.x;
    const int tid  = threadIdx.x;
    const int w    = tid >> 6;
    const int lane = tid & 63;
    const int q    = lane >> 4;
    const int l15  = lane & 15;

    // ---- W fragments: row = 64w + 16*tau + l15, k = 32*ki + 8q + j ----
    const __half* wbase = whh16 + ((size_t)(64 * w + l15)) * 512 + 8 * q;

    // tau0 + tau1 -> AGPR (asm-pinned; 128 acc regs, arch demand ~90 -> fits)
    half8 wA[32];
#pragma unroll
    for (int ta = 0; ta < 2; ++ta)
#pragma unroll
        for (int ki = 0; ki < 16; ++ki) {
            half8 v = *(const half8*)(wbase + (size_t)(16 * ta) * 512 + 32 * ki);
            asm volatile("" : "=a"(wA[ta * 16 + ki]) : "0"(v));
        }
    // tau2 ki0..14 -> LDS (per-wave contiguous 1 KB per set: conflict-free)
#pragma unroll
    for (int ki = 0; ki < ALD; ++ki) {
        half8 v = *(const half8*)(wbase + (size_t)32 * 512 + 32 * ki);
        *(half8*)&alds[(w * ALD + ki) * 512 + lane * 8] = v;
    }
    // zero h_0 into buffer 0
    {
        float4 z = {0.f, 0.f, 0.f, 0.f};
        *(float4*)&hlds[0][tid * 16]     = z;
        *(float4*)&hlds[0][tid * 16 + 8] = z;
    }
    __syncthreads();

    // chunk-layout index for (o = 64w+16*tau+4q+r, batch=l15):
    //   idx = (8w+2*tau+(q>>1))*128 + l15*8 + (q&1)*4 + r    (halfs)
    int cidx[4];
#pragma unroll
    for (int ta = 0; ta < 4; ++ta)
        cidx[ta] = (8 * w + 2 * ta + (q >> 1)) * 128 + l15 * 8 + (q & 1) * 4;

    const __half* xpb = xp16 + (size_t)bg * 8192;   // + t*32768 + cidx[ta]

    // direct out store: batch = bg*16+l15, o = 64w + 16*ta + 4q + r
    float* outr = out + (size_t)(bg * 16 + l15) * 512 + 64 * w + 4 * q;
    const size_t ostride = (size_t)BATCH * HID;

    // streamed-set loader: idx 0..15 = tau3 ki ; idx 16 = tau2 ki15
    auto ldW = [&](int idx) -> half8 {
        return (idx < 16)
            ? *(const half8*)(wbase + (size_t)48 * 512 + 32 * idx)
            : *(const half8*)(wbase + (size_t)32 * 512 + 32 * 15);
    };

    for (int t = 0; t < T_STEPS; ++t) {
        const _Float16* hread  = hlds[t & 1];
        _Float16*       hwrite = hlds[(t & 1) ^ 1];

        // xp for this step (consumed in phase B; latency hides under MFMA)
        uint2 xpv0 = *(const uint2*)(xpb + (size_t)t * 32768 + cidx[0]);
        uint2 xpv1 = *(const uint2*)(xpb + (size_t)t * 32768 + cidx[1]);
        uint2 xpv2 = *(const uint2*)(xpb + (size_t)t * 32768 + cidx[2]);
        uint2 xpv3 = *(const uint2*)(xpb + (size_t)t * 32768 + cidx[3]);

        f32x4 acc0 = {0.f, 0.f, 0.f, 0.f};
        f32x4 acc1 = {0.f, 0.f, 0.f, 0.f};
        f32x4 acc2 = {0.f, 0.f, 0.f, 0.f};
        f32x4 acc3 = {0.f, 0.f, 0.f, 0.f};

        // rolling streamed window: prefill 3 deep, then issue ki+3 at group ki
        half8 sW[17];
        sW[0] = ldW(0); sW[1] = ldW(1); sW[2] = ldW(2);

#pragma unroll
        for (int ki = 0; ki < 16; ++ki) {
            if (ki + 3 <= 16) sW[ki + 3] = ldW(ki + 3);
            half8 bfr = *(const half8*)&hread[(4 * ki + q) * 128 + l15 * 8];
            acc0 = __builtin_amdgcn_mfma_f32_16x16x32_f16(wA[ki],      bfr, acc0, 0, 0, 0);
            acc1 = __builtin_amdgcn_mfma_f32_16x16x32_f16(wA[16 + ki], bfr, acc1, 0, 0, 0);
            half8 w2;
            if (ki < ALD)
                w2 = *(const half8*)&alds[(w * ALD + ki) * 512 + lane * 8];
            else
                w2 = sW[16];
            acc2 = __builtin_amdgcn_mfma_f32_16x16x32_f16(w2,    bfr, acc2, 0, 0, 0);
            acc3 = __builtin_amdgcn_mfma_f32_16x16x32_f16(sW[ki], bfr, acc3, 0, 0, 0);
        }

        // ---- phase B: clamp-free tanh + h write (OTHER buffer) + out ----
        // tanh(s) = 1 - 2/(e^{2s}+1): exact at +/-inf, no clamp needed.
#pragma unroll
        for (int ta = 0; ta < 4; ++ta) {
            const uint2 xv = (ta == 0) ? xpv0 : (ta == 1) ? xpv1
                           : (ta == 2) ? xpv2 : xpv3;
            const half4v xh = __builtin_bit_cast(half4v, xv);
            const f32x4 A = (ta == 0) ? acc0 : (ta == 1) ? acc1
                          : (ta == 2) ? acc2 : acc3;
            half4v hv;
            float4 ov;
#pragma unroll
            for (int r = 0; r < 4; ++r) {
                const float s = A[r] + (float)xh[r];
                const float e = __expf(s + s);
                const float hnf = 1.f - 2.f * __builtin_amdgcn_rcpf(e + 1.f);
                hv[r] = (_Float16)hnf;
                ov[r] = hnf;
            }
            *(half4v*)&hwrite[cidx[ta]] = hv;
            *(float4*)(outr + (size_t)t * ostride + 16 * ta) = ov;
            if (t == T_STEPS - 1)
                *(float4*)(outr + (size_t)T_STEPS * ostride + 16 * ta) = ov;
        }
        __syncthreads();   // single barrier/step: h_t visible for next read
    }
}

// ---------------------------------------------------------------------------
// Scan v4 (mid-workspace fallback; reads f32 xproj from out in-place).
// ---------------------------------------------------------------------------
#define ACC4(WF, G) do {                                        \
    F4H hh_; hh_.f = *(const float4*)(hrow + (G) * 8);          \
    F4H ww_; ww_.f = (WF);                                      \
    a0 = dot2f(ww_.h[0], hh_.h[0], a0);                         \
    a1 = dot2f(ww_.h[1], hh_.h[1], a1);                         \
    a2 = dot2f(ww_.h[2], hh_.h[2], a2);                         \
    a3 = dot2f(ww_.h[3], hh_.h[3], a3); } while (0)

__global__ __launch_bounds__(512, 2)
void rnn_scan4(const __half* __restrict__ w16, float* __restrict__ out)
{
    __shared__ __align__(16) float4 wlds[SCH_LDS][HID];
    __shared__ __align__(16) __half hbuf[2][HID];

    const int b = blockIdx.x;
    const int j = threadIdx.x;

    const __half* wrow = w16 + (size_t)j * HID;

    float4 wreg[SCH_REG];
#pragma unroll
    for (int c = 0; c < SCH_REG; ++c)
        wreg[c] = *(const float4*)(wrow + c * 8);

#pragma unroll
    for (int c = 0; c < SCH_LDS; ++c)
        wlds[c][j] = *(const float4*)(wrow + (SCH_REG + c) * 8);

    hbuf[0][j] = __float2half(0.f);
    __syncthreads();

    float* outb = out + (size_t)b * HID + j;
    const size_t stride = (size_t)BATCH * HID;
    const __half* wstr = wrow + (SCH_REG + SCH_LDS) * 8;

    int cur = 0;
    float hn = 0.f;
    float xp_next = outb[0];

    for (int t = 0; t < T_STEPS; ++t) {
        const float xp = xp_next;
        const int tn = (t + 1 < T_STEPS) ? (t + 1) : t;
        xp_next = outb[(size_t)tn * stride];

        const __half* hrow = hbuf[cur];

        float4 wa[SCH_SA];
#pragma unroll
        for (int c = 0; c < SCH_SA; ++c)
            wa[c] = *(const float4*)(wstr + c * 8);

        float a0 = xp, a1 = 0.f, a2 = 0.f, a3 = 0.f;

#pragma unroll
        for (int c = 0; c < 20; ++c) ACC4(wreg[c], c);
#pragma unroll
        for (int c = 0; c < SCH_SA; ++c)
            ACC4(wa[c], SCH_REG + SCH_LDS + c);

        float4 wb[SCH_SB];
#pragma unroll
        for (int c = 0; c < SCH_SB; ++c)
            wb[c] = *(const float4*)(wstr + (SCH_SA + c) * 8);

#pragma unroll
        for (int c = 20; c < SCH_REG; ++c) ACC4(wreg[c], c);
#pragma unroll
        for (int c = 0; c < SCH_LDS; ++c) {
            float4 wfv = wlds[c][j];
            ACC4(wfv, SCH_REG + c);
        }

#pragma unroll
        for (int c = 0; c < SCH_SB; ++c)
            ACC4(wb[c], SCH_REG + SCH_LDS + SCH_SA + c);

        float s = (a0 + a1) + (a2 + a3);
        s = fminf(fmaxf(s, -15.f), 15.f);
        const float e = __expf(2.f * s);
        hn = (e - 1.f) * __builtin_amdgcn_rcpf(e + 1.f);

        outb[(size_t)t * stride] = hn;
        hbuf[cur ^ 1][j] = __float2half(hn);
        __syncthreads();
        cur ^= 1;
    }
    out[(size_t)T_STEPS * stride + (size_t)b * HID + j] = hn;
}

// ---------------------------------------------------------------------------
// Last-resort fp32 scan (no workspace needed).
// ---------------------------------------------------------------------------
__global__ __launch_bounds__(512) void rnn_scan_f32(const float* __restrict__ w,
                                                    float* __restrict__ out)
{
    __shared__ __align__(16) __half hs[2][HID];
    const int b = blockIdx.x;
    const int j = threadIdx.x;

    hs[0][j] = __float2half(0.f);
    __syncthreads();

    const float* wrow32 = w + (size_t)j * HID;
    float* outb = out + (size_t)b * HID + j;
    int cur = 0;
    float hn = 0.f;

    for (int t = 0; t < T_STEPS; ++t) {
        float a0 = outb[(size_t)t * (BATCH * HID)];
        float a1 = 0.f, a2 = 0.f, a3 = 0.f;
#pragma unroll 4
        for (int k0 = 0; k0 < HID; k0 += 8) {
            float4 w0 = *(const float4*)(wrow32 + k0);
            float4 w1 = *(const float4*)(wrow32 + k0 + 4);
            F4H h; h.f = *(const float4*)(&hs[cur][k0]);
            float2 h0 = __half22float2(*(__half2*)&h.h[0]);
            float2 h1 = __half22float2(*(__half2*)&h.h[1]);
            float2 h2 = __half22float2(*(__half2*)&h.h[2]);
            float2 h3 = __half22float2(*(__half2*)&h.h[3]);
            a0 = fmaf(w0.x, h0.x, a0); a1 = fmaf(w0.y, h0.y, a1);
            a2 = fmaf(w0.z, h1.x, a2); a3 = fmaf(w0.w, h1.y, a3);
            a0 = fmaf(w1.x, h2.x, a0); a1 = fmaf(w1.y, h2.y, a1);
            a2 = fmaf(w1.z, h3.x, a2); a3 = fmaf(w1.w, h3.y, a3);
        }
        hn = tanhf((a0 + a1) + (a2 + a3));
        outb[(size_t)t * (BATCH * HID)] = hn;
        hs[cur ^ 1][j] = __float2half(hn);
        __syncthreads();
        cur ^= 1;
    }
    out[(size_t)T_STEPS * BATCH * HID + (size_t)b * HID + j] = hn;
}

// ---------------------------------------------------------------------------
extern "C" void kernel_launch(void* const* d_in, const int* in_sizes, int n_in,
                              void* d_out, int out_size, void* d_ws, size_t ws_size,
                              hipStream_t stream) {
    const float* x    = (const float*)d_in[0];
    const float* w_ih = (const float*)d_in[1];
    const float* w_hh = (const float*)d_in[2];
    const float* b_ih = (const float*)d_in[3];
    const float* b_hh = (const float*)d_in[4];
    float* out = (float*)d_out;

    char* ws = (char*)d_ws;
    const bool full = ws_size >= (size_t)WS_FULL;
    const bool mid  = ws_size >= (size_t)WHH_BYTES;

    if (full) {
        __half*         xp16  = (__half*)(ws + XP16_OFF);
        unsigned short* wih16 = (unsigned short*)(ws + WIH_OFF);
        __half*         whh16 = (__half*)(ws + WHH_OFF);
        cvt_bf16<<<256, 256, 0, stream>>>(w_ih, wih16);
        cvt_f16 <<<256, 256, 0, stream>>>(w_hh, whh16);
        xproj_mfma<<<dim3(4, 256), 256, 0, stream>>>(x, wih16, b_ih, b_hh, xp16);
        rnn_scan11<<<4, 512, 0, stream>>>(whh16, xp16, out);
    } else if (mid) {
        __half* whh16 = (__half*)ws;
        cvt_f16<<<256, 256, 0, stream>>>(w_hh, whh16);
        xproj_gemm<<<dim3(8, 512), 256, 0, stream>>>(x, w_ih, b_ih, b_hh, out);
        rnn_scan4<<<BATCH, HID, 0, stream>>>(whh16, out);
    } else {
        xproj_gemm<<<dim3(8, 512), 256, 0, stream>>>(x, w_ih, b_ih, b_hh, out);
        rnn_scan_f32<<<BATCH, HID, 0, stream>>>(w_hh, out);
    }
}